// Round 6
// baseline (591.110 us; speedup 1.0000x reference)
//
#include <hip/hip_runtime.h>
#include <hip/hip_bf16.h>

typedef __attribute__((ext_vector_type(8))) short short8_t;
typedef __attribute__((ext_vector_type(8))) __bf16 bf16x8;
typedef __attribute__((ext_vector_type(4))) float f32x4;

__device__ __forceinline__ void gload16(const void* g, void* l) {
  __builtin_amdgcn_global_load_lds(
      (const __attribute__((address_space(1))) void*)g,
      (__attribute__((address_space(3))) void*)l, 16, 0, 0);
}

__device__ __forceinline__ unsigned short f2bf(float f) {
  __hip_bfloat16 h = __float2bfloat16(f);
  return __builtin_bit_cast(unsigned short, h);
}

#define BARRIER() asm volatile("s_barrier" ::: "memory")

// ---------------- conversion kernels ----------------

__global__ void k_cvt_feat(const float* __restrict__ in, unsigned short* __restrict__ out) {
  const size_t N = (size_t)4096 * 8192;
  size_t i = ((size_t)blockIdx.x * 256 + threadIdx.x) * 4;
  const size_t stride = (size_t)gridDim.x * 256 * 4;
  for (; i < N; i += stride) {
    float4 v = *(const float4*)(in + i);
    ushort4 o;
    o.x = f2bf(v.x); o.y = f2bf(v.y); o.z = f2bf(v.z); o.w = f2bf(v.w);
    *(ushort4*)(out + i) = o;
  }
}

// W1 f32 [p][8192][256] -> bf16 transposed chunk-local [z][256][8192]
// LDS tile [f=64][h=64], pad 65; vectorized ushort4 writes.
__global__ void k_cvt_w1(const float* __restrict__ W1, unsigned short* __restrict__ out, int p0) {
  __shared__ unsigned short t[64][65];
  const int p = p0 + blockIdx.z;
  const float* src = W1 + (size_t)p * 8192 * 256;
  unsigned short* dst = out + (size_t)blockIdx.z * 256 * 8192;
  const int f0 = blockIdx.x * 64, h0 = blockIdx.y * 64;
#pragma unroll
  for (int i = 0; i < 16; ++i) {
    int tt = i * 256 + threadIdx.x;
    int r = tt >> 6, c = tt & 63;                      // r: f, c: h (coalesced f32 read)
    t[r][c] = f2bf(src[(size_t)(f0 + r) * 256 + h0 + c]);
  }
  __syncthreads();
#pragma unroll
  for (int i = 0; i < 4; ++i) {
    int tt = i * 256 + threadIdx.x;
    int r = tt >> 4;                                   // h row
    int c4 = (tt & 15) * 4;                            // f col group of 4
    ushort4 o;
    o.x = t[c4][r]; o.y = t[c4 + 1][r]; o.z = t[c4 + 2][r]; o.w = t[c4 + 3][r];
    *(ushort4*)&dst[(size_t)(h0 + r) * 8192 + f0 + c4] = o;
  }
}

// W2 f32 [p][256][128] -> bf16 transposed [p][128][256]
__global__ void k_cvt_w2(const float* __restrict__ W2, unsigned short* __restrict__ out) {
  const int p = blockIdx.x;
  const float* src = W2 + (size_t)p * 256 * 128;
  unsigned short* dst = out + (size_t)p * 128 * 256;
  for (int tt = threadIdx.x; tt < 128 * 256; tt += 256) {
    int j = tt >> 8, h = tt & 255;
    dst[tt] = f2bf(src[(size_t)h * 128 + j]);
  }
}

// ---------------- GEMM1: h1 = relu(features @ W1 + b1) ----------------
// 256x256 tile, BK=32, 8 waves (2Mx4N, per-wave 128x64, acc[8][4]).
// 3-buffer LDS ring (3 x 32 KiB = 96 KiB), ONE barrier + ONE counted
// vmcnt(4) per K-tile; no intra-tile barriers (all reads hit buf[cur],
// stage writes buf[(t+2)%3] whose readers finished at the t-1 barrier).
//  tile t: stage(t+2) | 12 ds_read_b128 | setprio(1) 32 MFMA setprio(0)
//          | vmcnt(4)  (retires tile t+1's 4 loads, issued in tile t-1,
//            ~2 tile-bodies (~2500cy) earlier >= HBM latency) | BARRIER
// Waves drift freely inside the tile body -> ds_read overlaps MFMA
// across waves; compiler's partial lgkmcnt pipelines within a wave.
// LDS: row = 32 bf16 (4 units of 16B); unit u of row r at phys
// u ^ ((r>>1)&3) via pre-swizzled global source (rule 21); frag reads
// max 2-way bank aliasing per 16-lane group (free, m136).
__global__ __launch_bounds__(512, 2) void k_gemm1(
    const unsigned short* __restrict__ A,    // [4096][8192] bf16
    const unsigned short* __restrict__ Bt,   // [z][256][8192] bf16
    const float* __restrict__ b1,
    unsigned short* __restrict__ h1,
    int p0) {
  __shared__ __align__(16) unsigned short S[49152];  // 96 KiB: 3 x [A 8192 | B 8192]

  const int tid = threadIdx.x;
  const int lane = tid & 63;
  const int wave = tid >> 6;
  const int wm = wave >> 2;   // 0..1
  const int wn = wave & 3;    // 0..3

  // bijective chunked XCD swizzle; z-major: 16 consecutive wgs per XCD share
  // predicate z -> B panel (4MB) L2-resident.
  const int nwg = gridDim.x * gridDim.y;
  const int orig = blockIdx.y * gridDim.x + blockIdx.x;
  const int q = nwg >> 3, r_ = nwg & 7;
  const int xcd = orig & 7, idx = orig >> 3;
  const int wg = (xcd < r_ ? xcd * (q + 1) : r_ * (q + 1) + (xcd - r_) * q) + idx;
  const int mx = wg & 15;     // gridDim.x == 16
  const int z = wg >> 4;
  const int p = p0 + z;
  const int m0 = mx * 256;

  const unsigned short* Ab = A + (size_t)m0 * 8192;
  const unsigned short* Bb = Bt + (size_t)z * 256 * 8192;

  // staging: per matrix per tile 1024 units of 16B; thread covers units
  // e0=tid (rows 0..127), e1=512+tid (rows 128..255); r=e>>2, phys=e&3,
  // global unit u=(e&3)^((r>>1)&3)
  const int r0 = tid >> 2, u0 = (tid & 3) ^ ((r0 >> 1) & 3);
  const int r1 = 128 + (tid >> 2), u1 = (tid & 3) ^ ((r1 >> 1) & 3);
  const size_t sA0 = (size_t)r0 * 8192 + u0 * 8;
  const size_t sA1 = (size_t)r1 * 8192 + u1 * 8;
  const int ld0 = wave * 512;           // wave-uniform LDS short-offset
  const int ld1 = 4096 + wave * 512;

  auto stage = [&](int buf, int T) {
    const size_t ko = (size_t)T * 32;
    unsigned short* lb = S + buf * 16384;
    gload16(Ab + sA0 + ko, lb + ld0);
    gload16(Ab + sA1 + ko, lb + ld1);
    gload16(Bb + sA0 + ko, lb + 8192 + ld0);
    gload16(Bb + sA1 + ko, lb + 8192 + ld1);
  };

  const int l15 = lane & 15, ks = lane >> 4;

  auto rdA = [&](int buf, int mi) {
    int R = wm * 128 + mi * 16 + l15;
    int pu = ks ^ ((R >> 1) & 3);
    return __builtin_bit_cast(bf16x8, *(const short8_t*)(S + buf * 16384 + R * 32 + pu * 8));
  };
  auto rdB = [&](int buf, int nj) {
    int R = wn * 64 + nj * 16 + l15;
    int pu = ks ^ ((R >> 1) & 3);
    return __builtin_bit_cast(bf16x8, *(const short8_t*)(S + buf * 16384 + 8192 + R * 32 + pu * 8));
  };

  f32x4 acc[8][4] = {};
  const int NT = 8192 / 32;  // 256 K-tiles

  // prologue: tiles 0,1 staged; retire tile 0 (leave tile 1's 4 in flight)
  stage(0, 0);
  stage(1, 1);
  asm volatile("s_waitcnt vmcnt(4)" ::: "memory");
  BARRIER();

  int cur = 0, st = 2;
  for (int t = 0; t < NT; ++t) {
    if (t < NT - 2) stage(st, t + 2);
    bf16x8 af[8], bfv[4];
#pragma unroll
    for (int mi = 0; mi < 8; ++mi) af[mi] = rdA(cur, mi);
#pragma unroll
    for (int nj = 0; nj < 4; ++nj) bfv[nj] = rdB(cur, nj);
    __builtin_amdgcn_s_setprio(1);
#pragma unroll
    for (int mi = 0; mi < 8; ++mi)
#pragma unroll
      for (int nj = 0; nj < 4; ++nj)
        acc[mi][nj] = __builtin_amdgcn_mfma_f32_16x16x32_bf16(af[mi], bfv[nj], acc[mi][nj], 0, 0, 0);
    __builtin_amdgcn_s_setprio(0);
    if (t < NT - 2)       asm volatile("s_waitcnt vmcnt(4)" ::: "memory");
    else if (t == NT - 2) asm volatile("s_waitcnt vmcnt(0)" ::: "memory");
    BARRIER();
    cur = (cur == 2) ? 0 : cur + 1;
    st = (st == 2) ? 0 : st + 1;
  }

  // epilogue: + b1, relu, h1 bf16 [p][4096][256]
  const int rg = lane >> 4;
#pragma unroll
  for (int nj = 0; nj < 4; ++nj) {
    const int col = wn * 64 + nj * 16 + l15;
    const float bb = b1[p * 256 + col];
#pragma unroll
    for (int mi = 0; mi < 8; ++mi) {
      const int rbase = m0 + wm * 128 + mi * 16 + rg * 4;
#pragma unroll
      for (int rr = 0; rr < 4; ++rr) {
        float v = acc[mi][nj][rr] + bb;
        v = v > 0.f ? v : 0.f;
        h1[((size_t)p * 4096 + rbase + rr) * 256 + col] = f2bf(v);
      }
    }
  }
}

// ---------------- GEMM2+3 fused ----------------
__global__ __launch_bounds__(256, 2) void k_gemm23(
    const unsigned short* __restrict__ h1,   // [29][4096][256] bf16
    const unsigned short* __restrict__ W2t,  // [29][128][256] bf16
    const float* __restrict__ b2,
    const float* __restrict__ W3,
    const float* __restrict__ b3,
    float* __restrict__ out) {               // [4096][29]
  __shared__ __align__(16) unsigned short lds_a[128 * 64];
  __shared__ __align__(16) unsigned short lds_b[128 * 64];
  const int tid = threadIdx.x;
  const int lane = tid & 63;
  const int wave = tid >> 6;
  const int m0 = blockIdx.x * 128;
  const int p = blockIdx.y;

  const unsigned short* Ab = h1 + ((size_t)p * 4096 + m0) * 256;
  const unsigned short* Bb = W2t + (size_t)p * 128 * 256;

  f32x4 acc[2][8] = {};

  for (int k0 = 0; k0 < 256; k0 += 64) {
    __syncthreads();
#pragma unroll
    for (int i = 0; i < 4; ++i) {
      int t = i * 256 + tid;
      int r = t >> 3;
      int uu = (t & 7) ^ (r & 7);
      gload16(Ab + (size_t)r * 256 + k0 + uu * 8, &lds_a[(i * 256 + wave * 64) * 8]);
      gload16(Bb + (size_t)r * 256 + k0 + uu * 8, &lds_b[(i * 256 + wave * 64) * 8]);
    }
    __syncthreads();
#pragma unroll
    for (int kk = 0; kk < 64; kk += 32) {
      const int ku = (kk >> 3) + (lane >> 4);
      bf16x8 af[2], bfv[8];
#pragma unroll
      for (int mi = 0; mi < 2; ++mi) {
        int row = wave * 32 + mi * 16 + (lane & 15);
        int u = ku ^ (row & 7);
        af[mi] = __builtin_bit_cast(bf16x8, *(const short8_t*)&lds_a[row * 64 + u * 8]);
      }
#pragma unroll
      for (int nj = 0; nj < 8; ++nj) {
        int row = nj * 16 + (lane & 15);
        int u = ku ^ (row & 7);
        bfv[nj] = __builtin_bit_cast(bf16x8, *(const short8_t*)&lds_b[row * 64 + u * 8]);
      }
#pragma unroll
      for (int mi = 0; mi < 2; ++mi)
#pragma unroll
        for (int nj = 0; nj < 8; ++nj)
          acc[mi][nj] = __builtin_amdgcn_mfma_f32_16x16x32_bf16(af[mi], bfv[nj], acc[mi][nj], 0, 0, 0);
    }
  }

  float b2v[8], w3v[8];
  const int c16 = lane & 15;
#pragma unroll
  for (int nj = 0; nj < 8; ++nj) {
    int c = nj * 16 + c16;
    b2v[nj] = b2[p * 128 + c];
    w3v[nj] = W3[p * 128 + c];
  }
  const float b3p = b3[p];
#pragma unroll
  for (int mi = 0; mi < 2; ++mi) {
#pragma unroll
    for (int r = 0; r < 4; ++r) {
      float s = 0.f;
#pragma unroll
      for (int nj = 0; nj < 8; ++nj) {
        float v = acc[mi][nj][r] + b2v[nj];
        v = v > 0.f ? v : 0.f;
        s += v * w3v[nj];
      }
      s += __shfl_xor(s, 1);
      s += __shfl_xor(s, 2);
      s += __shfl_xor(s, 4);
      s += __shfl_xor(s, 8);
      if ((lane & 15) == 0) {
        int m = m0 + wave * 32 + mi * 16 + (lane >> 4) * 4 + r;
        float logit = s + b3p;
        out[(size_t)m * 29 + p] = 1.f / (1.f + __expf(-logit));
      }
    }
  }
}

// ---------------- launch ----------------
extern "C" void kernel_launch(void* const* d_in, const int* in_sizes, int n_in,
                              void* d_out, int out_size, void* d_ws, size_t ws_size,
                              hipStream_t stream) {
  const float* features = (const float*)d_in[0];
  const float* W1 = (const float*)d_in[1];
  const float* b1 = (const float*)d_in[2];
  const float* W2 = (const float*)d_in[3];
  const float* b2 = (const float*)d_in[4];
  const float* W3 = (const float*)d_in[5];
  const float* b3 = (const float*)d_in[6];
  float* out = (float*)d_out;

  char* ws = (char*)d_ws;
  const size_t featB = (size_t)4096 * 8192 * 2;       // 64 MB
  const size_t h1B   = (size_t)29 * 4096 * 256 * 2;   // 58 MB
  const size_t w2B   = (size_t)29 * 128 * 256 * 2;    // 1.9 MB
  const size_t w1pp  = (size_t)256 * 8192 * 2;        // 4 MB per predicate

  unsigned short* featbf = (unsigned short*)ws;
  unsigned short* h1bf   = (unsigned short*)(ws + featB);
  unsigned short* w2t    = (unsigned short*)(ws + featB + h1B);
  unsigned short* w1t    = (unsigned short*)(ws + featB + h1B + w2B);

  size_t base = featB + h1B + w2B;
  size_t rem = (ws_size > base) ? (ws_size - base) : 0;
  int CH = (int)(rem / w1pp);
  if (CH > 29) CH = 29;
  if (CH < 1) CH = 1;

  k_cvt_feat<<<2048, 256, 0, stream>>>(features, featbf);
  k_cvt_w2<<<29, 256, 0, stream>>>(W2, w2t);

  for (int p0 = 0; p0 < 29; p0 += CH) {
    int c = (29 - p0) < CH ? (29 - p0) : CH;
    k_cvt_w1<<<dim3(128, 4, c), 256, 0, stream>>>(W1, w1t, p0);
    k_gemm1<<<dim3(16, c), 512, 0, stream>>>(featbf, w1t, b1, h1bf, p0);
  }

  k_gemm23<<<dim3(32, 29), 256, 0, stream>>>(h1bf, w2t, b2, W3, b3, out);
}